// Round 1
// baseline (756.172 us; speedup 1.0000x reference)
//
#include <hip/hip_runtime.h>

#define HID 128

// ---------------- CSR build ----------------

__global__ void init_kernel(int* degi, float* pool, float* cnt, int n) {
    int i = blockIdx.x * 256 + threadIdx.x;
    if (i < n) degi[i] = 1;              // self-loop
    if (i < 128 * 128) pool[i] = 0.f;
    if (i < 128) cnt[i] = 0.f;
}

__global__ void count_kernel(const int* __restrict__ ei, int* degi, int E) {
    int e = blockIdx.x * 256 + threadIdx.x;
    if (e < E) atomicAdd(&degi[ei[E + e]], 1);   // col = dest
}

__global__ void dinv_kernel(const int* __restrict__ degi, float* dinv, int n) {
    int i = blockIdx.x * 256 + threadIdx.x;
    if (i < n) dinv[i] = rsqrtf((float)degi[i]); // deg >= 1 always (self-loop)
}

__global__ __launch_bounds__(1024) void scan_kernel(const int* __restrict__ degi,
                                                    int* rp, int* cursor, int n) {
    int tid = threadIdx.x;
    int chunk = (n + 1023) >> 10;
    int base = tid * chunk;
    int end = base + chunk; if (end > n) end = n;
    int s = 0;
    for (int i = base; i < end; ++i) s += degi[i];
    // block-wide inclusive scan of s
    int lane = tid & 63, wid = tid >> 6;
    int x = s;
    #pragma unroll
    for (int off = 1; off < 64; off <<= 1) {
        int y = __shfl_up(x, off);
        if (lane >= off) x += y;
    }
    __shared__ int wsum[16];
    if (lane == 63) wsum[wid] = x;
    __syncthreads();
    if (tid < 16) {
        int y = wsum[tid];
        #pragma unroll
        for (int off = 1; off < 16; off <<= 1) {
            int z = __shfl_up(y, off);
            if (tid >= off) y += z;
        }
        wsum[tid] = y;
    }
    __syncthreads();
    int excl = x - s + (wid > 0 ? wsum[wid - 1] : 0);
    int run = excl;
    for (int i = base; i < end; ++i) {
        rp[i] = run; cursor[i] = run; run += degi[i];
    }
    if (tid == 0) rp[n] = wsum[15];
}

__global__ void fill_kernel(const int* __restrict__ ei, const float* __restrict__ dinv,
                            int* cursor, int* csr_src, float* csr_w, int E, int n) {
    int e = blockIdx.x * 256 + threadIdx.x;
    if (e >= E + n) return;
    int r, c;
    if (e < E) { r = ei[e]; c = ei[E + e]; }
    else       { r = e - E; c = r; }          // self-loop
    int pos = atomicAdd(&cursor[c], 1);
    csr_src[pos] = r;
    csr_w[pos] = dinv[r] * dinv[c];
}

// ---------------- fp32 GEMM: C[n x 128] = A[n x 128] @ W[128 x 128] ----------------
// 128-row block tile, BK=32, 256 threads, 8x8 register tile per thread.

__global__ __launch_bounds__(256) void gemm_kernel(const float* __restrict__ A,
                                                   const float* __restrict__ W,
                                                   float* __restrict__ C, int n) {
    __shared__ float As[32 * 132];   // As[k][r], padded stride 132
    __shared__ float Bs[32 * 128];   // Bs[k][c]
    int tid = threadIdx.x;
    int tx = tid & 15, ty = tid >> 4;
    int rowBase = blockIdx.x * 128;
    int r0 = ty * 8, c0 = tx * 8;
    float acc[8][8] = {};
    for (int kb = 0; kb < 4; ++kb) {
        // stage A^T chunk: As[k][r] = A[rowBase+r][kb*32+k]
        #pragma unroll
        for (int q = 0; q < 4; ++q) {
            int f = q * 256 + tid;       // 0..1023 float4 slots
            int row = f >> 3;            // 0..127
            int k4 = f & 7;              // 0..7
            int grow = rowBase + row;
            float4 v = make_float4(0.f, 0.f, 0.f, 0.f);
            if (grow < n) v = *(const float4*)&A[grow * 128 + kb * 32 + k4 * 4];
            As[(k4 * 4 + 0) * 132 + row] = v.x;
            As[(k4 * 4 + 1) * 132 + row] = v.y;
            As[(k4 * 4 + 2) * 132 + row] = v.z;
            As[(k4 * 4 + 3) * 132 + row] = v.w;
        }
        // stage W chunk: Bs[k][c] = W[kb*32+k][c]
        #pragma unroll
        for (int q = 0; q < 4; ++q) {
            int f = q * 256 + tid;
            int k = f >> 5; int c4 = f & 31;
            *(float4*)&Bs[k * 128 + c4 * 4] = *(const float4*)&W[(kb * 32 + k) * 128 + c4 * 4];
        }
        __syncthreads();
        #pragma unroll 8
        for (int k = 0; k < 32; ++k) {
            float4 a0 = *(float4*)&As[k * 132 + r0];
            float4 a1 = *(float4*)&As[k * 132 + r0 + 4];
            float4 b0 = *(float4*)&Bs[k * 128 + c0];
            float4 b1 = *(float4*)&Bs[k * 128 + c0 + 4];
            float a[8] = {a0.x, a0.y, a0.z, a0.w, a1.x, a1.y, a1.z, a1.w};
            float b[8] = {b0.x, b0.y, b0.z, b0.w, b1.x, b1.y, b1.z, b1.w};
            #pragma unroll
            for (int i = 0; i < 8; ++i)
                #pragma unroll
                for (int j = 0; j < 8; ++j)
                    acc[i][j] += a[i] * b[j];
        }
        __syncthreads();
    }
    #pragma unroll
    for (int i = 0; i < 8; ++i) {
        int grow = rowBase + r0 + i;
        if (grow < n) {
            *(float4*)&C[grow * 128 + c0]     = make_float4(acc[i][0], acc[i][1], acc[i][2], acc[i][3]);
            *(float4*)&C[grow * 128 + c0 + 4] = make_float4(acc[i][4], acc[i][5], acc[i][6], acc[i][7]);
        }
    }
}

// ---------------- aggregation: h[j] = relu(b + sum_p w[p] * t[src[p]]) ----------------

__global__ __launch_bounds__(128) void agg_kernel(const float* __restrict__ t,
                                                  const float* __restrict__ bias,
                                                  const int* __restrict__ rp,
                                                  const int* __restrict__ src,
                                                  const float* __restrict__ w,
                                                  float* __restrict__ hout, int n) {
    int j = blockIdx.x;
    int c = threadIdx.x;
    int p0 = rp[j], p1 = rp[j + 1];
    float acc = 0.f;
    int p = p0;
    for (; p + 4 <= p1; p += 4) {
        int s0 = src[p], s1 = src[p + 1], s2 = src[p + 2], s3 = src[p + 3];
        float w0 = w[p], w1 = w[p + 1], w2 = w[p + 2], w3 = w[p + 3];
        float v0 = t[s0 * 128 + c], v1 = t[s1 * 128 + c];
        float v2 = t[s2 * 128 + c], v3 = t[s3 * 128 + c];
        acc += w0 * v0 + w1 * v1 + w2 * v2 + w3 * v3;
    }
    for (; p < p1; ++p) acc += w[p] * t[src[p] * 128 + c];
    hout[j * 128 + c] = fmaxf(acc + bias[c], 0.f);
}

// ---------------- pooling (batch sorted: run-length partials) ----------------

__global__ __launch_bounds__(128) void pool_kernel(const float* __restrict__ t,
                                                   const float* __restrict__ bfc,
                                                   const int* __restrict__ batch,
                                                   float* pool, float* cnt, int n) {
    int c = threadIdx.x;
    int j0 = blockIdx.x * 128;
    if (j0 >= n) return;
    int jend = j0 + 128; if (jend > n) jend = n;
    int g_prev = batch[j0];
    float acc = 0.f; int run = 0;
    for (int j = j0; j < jend; ++j) {
        int g = batch[j];
        if (g != g_prev) {
            atomicAdd(&pool[g_prev * 128 + c], acc);
            if (c == 0) atomicAdd(&cnt[g_prev], (float)run);
            acc = 0.f; run = 0; g_prev = g;
        }
        acc += fmaxf(t[j * 128 + c] + bfc[c], 0.f);
        run++;
    }
    atomicAdd(&pool[g_prev * 128 + c], acc);
    if (c == 0) atomicAdd(&cnt[g_prev], (float)run);
}

// ---------------- final: embeddings + logits ----------------

__global__ __launch_bounds__(128) void final_kernel(const float* __restrict__ pool,
                                                    const float* __restrict__ cnt,
                                                    const float* __restrict__ Wlin,
                                                    const float* __restrict__ blin,
                                                    float* __restrict__ out) {
    int g = blockIdx.x;
    int c = threadIdx.x;
    __shared__ float p[128];
    float pv = pool[g * 128 + c] / fmaxf(cnt[g], 1.0f);
    out[1280 + g * 128 + c] = pv;   // embeddings after logits (128*10 = 1280)
    p[c] = pv;
    __syncthreads();
    if (c < 10) {
        float acc = blin[c];
        for (int k = 0; k < 128; ++k) acc += p[k] * Wlin[k * 10 + c];
        out[g * 10 + c] = acc;
    }
}

// ---------------- launch ----------------

extern "C" void kernel_launch(void* const* d_in, const int* in_sizes, int n_in,
                              void* d_out, int out_size, void* d_ws, size_t ws_size,
                              hipStream_t stream) {
    const float* x     = (const float*)d_in[0];
    const int*   ei    = (const int*)d_in[1];
    const int*   batch = (const int*)d_in[2];
    const float* Wl[6] = {(const float*)d_in[3], (const float*)d_in[5], (const float*)d_in[7],
                          (const float*)d_in[9], (const float*)d_in[11], (const float*)d_in[13]};
    const float* bl[6] = {(const float*)d_in[4], (const float*)d_in[6], (const float*)d_in[8],
                          (const float*)d_in[10], (const float*)d_in[12], (const float*)d_in[14]};
    const float* Wlin = (const float*)d_in[15];
    const float* blin = (const float*)d_in[16];

    const int N = in_sizes[2];        // 50000
    const int E = in_sizes[1] / 2;    // 600000
    (void)n_in; (void)out_size; (void)ws_size;

    char* p = (char*)d_ws;
    auto carve = [&](size_t bytes) { void* r = (void*)p; p += (bytes + 255) & ~(size_t)255; return r; };
    float* hA      = (float*)carve((size_t)N * 128 * 4);
    float* tB      = (float*)carve((size_t)N * 128 * 4);
    int*   degi    = (int*)carve((size_t)N * 4);
    float* dinv    = (float*)carve((size_t)N * 4);
    int*   rp      = (int*)carve((size_t)(N + 1) * 4);
    int*   cursor  = (int*)carve((size_t)N * 4);
    int*   csr_src = (int*)carve((size_t)(E + N) * 4);
    float* csr_w   = (float*)carve((size_t)(E + N) * 4);
    float* pool    = (float*)carve(128 * 128 * 4);
    float* cnt     = (float*)carve(128 * 4);

    int gN = (N + 255) / 256;
    init_kernel<<<gN, 256, 0, stream>>>(degi, pool, cnt, N);
    count_kernel<<<(E + 255) / 256, 256, 0, stream>>>(ei, degi, E);
    dinv_kernel<<<gN, 256, 0, stream>>>(degi, dinv, N);
    scan_kernel<<<1, 1024, 0, stream>>>(degi, rp, cursor, N);
    fill_kernel<<<(E + N + 255) / 256, 256, 0, stream>>>(ei, dinv, cursor, csr_src, csr_w, E, N);

    int gGemm = (N + 127) / 128;
    const float* hin = x;
    for (int l = 0; l < 5; ++l) {
        gemm_kernel<<<gGemm, 256, 0, stream>>>(hin, Wl[l], tB, N);
        agg_kernel<<<N, 128, 0, stream>>>(tB, bl[l], rp, csr_src, csr_w, hA, N);
        hin = hA;
    }
    gemm_kernel<<<gGemm, 256, 0, stream>>>(hA, Wl[5], tB, N);          // FC matmul
    pool_kernel<<<(N + 127) / 128, 128, 0, stream>>>(tB, bl[5], batch, pool, cnt, N);
    final_kernel<<<128, 128, 0, stream>>>(pool, cnt, Wlin, blin, (float*)d_out);
}

// Round 2
// 654.297 us; speedup vs baseline: 1.1557x; 1.1557x over previous
//
#include <hip/hip_runtime.h>

#define HID 128

// ---------------- CSR build ----------------

__global__ void init_kernel(int* degi, float* pool, float* cnt, int n) {
    int i = blockIdx.x * 256 + threadIdx.x;
    if (i < n) degi[i] = 1;              // self-loop
    if (i < 128 * 128) pool[i] = 0.f;
    if (i < 128) cnt[i] = 0.f;
}

__global__ void count_kernel(const int* __restrict__ ei, int* degi, int E) {
    int e = blockIdx.x * 256 + threadIdx.x;
    if (e < E) atomicAdd(&degi[ei[E + e]], 1);   // col = dest
}

__global__ void dinv_kernel(const int* __restrict__ degi, float* dinv, int n) {
    int i = blockIdx.x * 256 + threadIdx.x;
    if (i < n) dinv[i] = rsqrtf((float)degi[i]); // deg >= 1 always (self-loop)
}

// --- parallel scan: phase 1, per-block sums of 256 degrees ---
__global__ __launch_bounds__(256) void scan_bsum_kernel(const int* __restrict__ degi,
                                                        int* bsum, int n) {
    int tid = threadIdx.x;
    int i = blockIdx.x * 256 + tid;
    int v = (i < n) ? degi[i] : 0;
    // wave reduce
    #pragma unroll
    for (int off = 32; off > 0; off >>= 1) v += __shfl_down(v, off);
    __shared__ int ws[4];
    if ((tid & 63) == 0) ws[tid >> 6] = v;
    __syncthreads();
    if (tid == 0) bsum[blockIdx.x] = ws[0] + ws[1] + ws[2] + ws[3];
}

// --- phase 2: exclusive scan of block sums (nb <= 256), single block ---
__global__ __launch_bounds__(256) void scan_sums_kernel(const int* __restrict__ bsum,
                                                        int* boff, int nb) {
    int tid = threadIdx.x;
    int v = (tid < nb) ? bsum[tid] : 0;
    int lane = tid & 63, wid = tid >> 6;
    int x = v;
    #pragma unroll
    for (int off = 1; off < 64; off <<= 1) {
        int y = __shfl_up(x, off);
        if (lane >= off) x += y;
    }
    __shared__ int ws[4];
    if (lane == 63) ws[wid] = x;
    __syncthreads();
    if (tid == 0) { int a = 0; for (int j = 0; j < 4; ++j) { int t = ws[j]; ws[j] = a; a += t; } }
    __syncthreads();
    if (tid < nb) boff[tid] = x - v + ws[wid];   // exclusive
}

// --- phase 3: per-block exclusive scan + emit rp/cursor ---
__global__ __launch_bounds__(256) void scan_emit_kernel(const int* __restrict__ degi,
                                                        const int* __restrict__ boff,
                                                        int* rp, int* cursor, int n) {
    int tid = threadIdx.x;
    int i = blockIdx.x * 256 + tid;
    int v = (i < n) ? degi[i] : 0;
    int lane = tid & 63, wid = tid >> 6;
    int x = v;
    #pragma unroll
    for (int off = 1; off < 64; off <<= 1) {
        int y = __shfl_up(x, off);
        if (lane >= off) x += y;
    }
    __shared__ int ws[4];
    if (lane == 63) ws[wid] = x;
    __syncthreads();
    if (tid == 0) { int a = 0; for (int j = 0; j < 4; ++j) { int t = ws[j]; ws[j] = a; a += t; } }
    __syncthreads();
    int excl = x - v + ws[wid] + boff[blockIdx.x];
    if (i < n) { rp[i] = excl; cursor[i] = excl; }
    if (i == n - 1) rp[n] = excl + v;
}

__global__ void fill_kernel(const int* __restrict__ ei, const float* __restrict__ dinv,
                            int* cursor, int* csr_src, float* csr_w, int E, int n) {
    int e = blockIdx.x * 256 + threadIdx.x;
    if (e >= E + n) return;
    int r, c;
    if (e < E) { r = ei[e]; c = ei[E + e]; }
    else       { r = e - E; c = r; }          // self-loop
    int pos = atomicAdd(&cursor[c], 1);
    csr_src[pos] = r;
    csr_w[pos] = dinv[r] * dinv[c];
}

// ---------------- fp32 GEMM: C[n x 128] = A[n x 128] @ W[128 x 128] ----------------
// 128-row block tile, BK=32, 256 threads, 8x8 register tile per thread.

__global__ __launch_bounds__(256) void gemm_kernel(const float* __restrict__ A,
                                                   const float* __restrict__ W,
                                                   float* __restrict__ C, int n) {
    __shared__ float As[32 * 132];   // As[k][r], padded stride 132
    __shared__ float Bs[32 * 128];   // Bs[k][c]
    int tid = threadIdx.x;
    int tx = tid & 15, ty = tid >> 4;
    int rowBase = blockIdx.x * 128;
    int r0 = ty * 8, c0 = tx * 8;
    float acc[8][8] = {};
    for (int kb = 0; kb < 4; ++kb) {
        // stage A^T chunk: As[k][r] = A[rowBase+r][kb*32+k]
        #pragma unroll
        for (int q = 0; q < 4; ++q) {
            int f = q * 256 + tid;       // 0..1023 float4 slots
            int row = f >> 3;            // 0..127
            int k4 = f & 7;              // 0..7
            int grow = rowBase + row;
            float4 v = make_float4(0.f, 0.f, 0.f, 0.f);
            if (grow < n) v = *(const float4*)&A[grow * 128 + kb * 32 + k4 * 4];
            As[(k4 * 4 + 0) * 132 + row] = v.x;
            As[(k4 * 4 + 1) * 132 + row] = v.y;
            As[(k4 * 4 + 2) * 132 + row] = v.z;
            As[(k4 * 4 + 3) * 132 + row] = v.w;
        }
        // stage W chunk: Bs[k][c] = W[kb*32+k][c]
        #pragma unroll
        for (int q = 0; q < 4; ++q) {
            int f = q * 256 + tid;
            int k = f >> 5; int c4 = f & 31;
            *(float4*)&Bs[k * 128 + c4 * 4] = *(const float4*)&W[(kb * 32 + k) * 128 + c4 * 4];
        }
        __syncthreads();
        #pragma unroll 8
        for (int k = 0; k < 32; ++k) {
            float4 a0 = *(float4*)&As[k * 132 + r0];
            float4 a1 = *(float4*)&As[k * 132 + r0 + 4];
            float4 b0 = *(float4*)&Bs[k * 128 + c0];
            float4 b1 = *(float4*)&Bs[k * 128 + c0 + 4];
            float a[8] = {a0.x, a0.y, a0.z, a0.w, a1.x, a1.y, a1.z, a1.w};
            float b[8] = {b0.x, b0.y, b0.z, b0.w, b1.x, b1.y, b1.z, b1.w};
            #pragma unroll
            for (int i = 0; i < 8; ++i)
                #pragma unroll
                for (int j = 0; j < 8; ++j)
                    acc[i][j] += a[i] * b[j];
        }
        __syncthreads();
    }
    #pragma unroll
    for (int i = 0; i < 8; ++i) {
        int grow = rowBase + r0 + i;
        if (grow < n) {
            *(float4*)&C[grow * 128 + c0]     = make_float4(acc[i][0], acc[i][1], acc[i][2], acc[i][3]);
            *(float4*)&C[grow * 128 + c0 + 4] = make_float4(acc[i][4], acc[i][5], acc[i][6], acc[i][7]);
        }
    }
}

// ---------------- aggregation: h[j] = relu(b + sum_p w[p] * t[src[p]]) ----------------
// 32 threads per node (float4 per thread), 8 nodes per 256-thread block.

__global__ __launch_bounds__(256) void agg_kernel(const float* __restrict__ t,
                                                  const float* __restrict__ bias,
                                                  const int* __restrict__ rp,
                                                  const int* __restrict__ src,
                                                  const float* __restrict__ w,
                                                  float* __restrict__ hout, int n) {
    int local = threadIdx.x & 31;
    int j = blockIdx.x * 8 + (threadIdx.x >> 5);
    if (j >= n) return;
    int c4 = local * 4;
    int p0 = rp[j], p1 = rp[j + 1];
    float4 acc0 = make_float4(0.f, 0.f, 0.f, 0.f);
    float4 acc1 = make_float4(0.f, 0.f, 0.f, 0.f);
    int p = p0;
    for (; p + 2 <= p1; p += 2) {
        int s0 = src[p], s1 = src[p + 1];
        float w0 = w[p], w1 = w[p + 1];
        float4 v0 = *(const float4*)&t[s0 * 128 + c4];
        float4 v1 = *(const float4*)&t[s1 * 128 + c4];
        acc0.x += w0 * v0.x; acc0.y += w0 * v0.y; acc0.z += w0 * v0.z; acc0.w += w0 * v0.w;
        acc1.x += w1 * v1.x; acc1.y += w1 * v1.y; acc1.z += w1 * v1.z; acc1.w += w1 * v1.w;
    }
    if (p < p1) {
        int s0 = src[p]; float w0 = w[p];
        float4 v0 = *(const float4*)&t[s0 * 128 + c4];
        acc0.x += w0 * v0.x; acc0.y += w0 * v0.y; acc0.z += w0 * v0.z; acc0.w += w0 * v0.w;
    }
    float4 b = *(const float4*)&bias[c4];
    float4 o;
    o.x = fmaxf(acc0.x + acc1.x + b.x, 0.f);
    o.y = fmaxf(acc0.y + acc1.y + b.y, 0.f);
    o.z = fmaxf(acc0.z + acc1.z + b.z, 0.f);
    o.w = fmaxf(acc0.w + acc1.w + b.w, 0.f);
    *(float4*)&hout[j * 128 + c4] = o;
}

// ---------------- pooling (batch sorted: run-length partials) ----------------

__global__ __launch_bounds__(128) void pool_kernel(const float* __restrict__ t,
                                                   const float* __restrict__ bfc,
                                                   const int* __restrict__ batch,
                                                   float* pool, float* cnt, int n) {
    int c = threadIdx.x;
    int j0 = blockIdx.x * 128;
    if (j0 >= n) return;
    int jend = j0 + 128; if (jend > n) jend = n;
    int g_prev = batch[j0];
    float acc = 0.f; int run = 0;
    for (int j = j0; j < jend; ++j) {
        int g = batch[j];
        if (g != g_prev) {
            atomicAdd(&pool[g_prev * 128 + c], acc);
            if (c == 0) atomicAdd(&cnt[g_prev], (float)run);
            acc = 0.f; run = 0; g_prev = g;
        }
        acc += fmaxf(t[j * 128 + c] + bfc[c], 0.f);
        run++;
    }
    atomicAdd(&pool[g_prev * 128 + c], acc);
    if (c == 0) atomicAdd(&cnt[g_prev], (float)run);
}

// ---------------- final: embeddings + logits ----------------

__global__ __launch_bounds__(128) void final_kernel(const float* __restrict__ pool,
                                                    const float* __restrict__ cnt,
                                                    const float* __restrict__ Wlin,
                                                    const float* __restrict__ blin,
                                                    float* __restrict__ out) {
    int g = blockIdx.x;
    int c = threadIdx.x;
    __shared__ float p[128];
    float pv = pool[g * 128 + c] / fmaxf(cnt[g], 1.0f);
    out[1280 + g * 128 + c] = pv;   // embeddings after logits (128*10 = 1280)
    p[c] = pv;
    __syncthreads();
    if (c < 10) {
        float acc = blin[c];
        for (int k = 0; k < 128; ++k) acc += p[k] * Wlin[k * 10 + c];
        out[g * 10 + c] = acc;
    }
}

// ---------------- launch ----------------

extern "C" void kernel_launch(void* const* d_in, const int* in_sizes, int n_in,
                              void* d_out, int out_size, void* d_ws, size_t ws_size,
                              hipStream_t stream) {
    const float* x     = (const float*)d_in[0];
    const int*   ei    = (const int*)d_in[1];
    const int*   batch = (const int*)d_in[2];
    const float* Wl[6] = {(const float*)d_in[3], (const float*)d_in[5], (const float*)d_in[7],
                          (const float*)d_in[9], (const float*)d_in[11], (const float*)d_in[13]};
    const float* bl[6] = {(const float*)d_in[4], (const float*)d_in[6], (const float*)d_in[8],
                          (const float*)d_in[10], (const float*)d_in[12], (const float*)d_in[14]};
    const float* Wlin = (const float*)d_in[15];
    const float* blin = (const float*)d_in[16];

    const int N = in_sizes[2];        // 50000
    const int E = in_sizes[1] / 2;    // 600000
    (void)n_in; (void)out_size; (void)ws_size;

    char* p = (char*)d_ws;
    auto carve = [&](size_t bytes) { void* r = (void*)p; p += (bytes + 255) & ~(size_t)255; return r; };
    float* hA      = (float*)carve((size_t)N * 128 * 4);
    float* tB      = (float*)carve((size_t)N * 128 * 4);
    int*   degi    = (int*)carve((size_t)N * 4);
    float* dinv    = (float*)carve((size_t)N * 4);
    int*   rp      = (int*)carve((size_t)(N + 1) * 4);
    int*   cursor  = (int*)carve((size_t)N * 4);
    int*   csr_src = (int*)carve((size_t)(E + N) * 4);
    float* csr_w   = (float*)carve((size_t)(E + N) * 4);
    float* pool    = (float*)carve(128 * 128 * 4);
    float* cnt     = (float*)carve(128 * 4);
    int*   bsum    = (int*)carve(256 * 4);
    int*   boff    = (int*)carve(256 * 4);

    int gN = (N + 255) / 256;
    init_kernel<<<gN, 256, 0, stream>>>(degi, pool, cnt, N);
    count_kernel<<<(E + 255) / 256, 256, 0, stream>>>(ei, degi, E);
    dinv_kernel<<<gN, 256, 0, stream>>>(degi, dinv, N);
    int nb = gN;   // 196 blocks of 256
    scan_bsum_kernel<<<nb, 256, 0, stream>>>(degi, bsum, N);
    scan_sums_kernel<<<1, 256, 0, stream>>>(bsum, boff, nb);
    scan_emit_kernel<<<nb, 256, 0, stream>>>(degi, boff, rp, cursor, N);
    fill_kernel<<<(E + N + 255) / 256, 256, 0, stream>>>(ei, dinv, cursor, csr_src, csr_w, E, N);

    int gGemm = (N + 127) / 128;
    const float* hin = x;
    for (int l = 0; l < 5; ++l) {
        gemm_kernel<<<gGemm, 256, 0, stream>>>(hin, Wl[l], tB, N);
        agg_kernel<<<(N + 7) / 8, 256, 0, stream>>>(tB, bl[l], rp, csr_src, csr_w, hA, N);
        hin = hA;
    }
    gemm_kernel<<<gGemm, 256, 0, stream>>>(hA, Wl[5], tB, N);          // FC matmul
    pool_kernel<<<(N + 127) / 128, 128, 0, stream>>>(tB, bl[5], batch, pool, cnt, N);
    final_kernel<<<128, 128, 0, stream>>>(pool, cnt, Wlin, blin, (float*)d_out);
}